// Round 1
// baseline (756.554 us; speedup 1.0000x reference)
//
#include <hip/hip_runtime.h>
#include <math.h>

// irreps: (256,1)@0, (256,3)@256, (128,5)@1024, (64,7)@1664 ; DIM=2112, OUT=704
// Task decomposition: 1 task = 4 consecutive outputs of one irrep class
//   class d=1: 64 tasks/row (1 float4 load,  fabs)
//   class d=3: 64 tasks/row (3 float4 loads)
//   class d=5: 32 tasks/row (5 float4 loads)
//   class d=7: 16 tasks/row (7 float4 loads)
// Tasks are ordered class-major across the whole batch -> bit-op indexing,
// branch-uniform waves, all loads/stores are aligned float4. No LDS/barriers.

#define ROW4  528   // 2112 floats / 4
#define OUT4  176   // 704 floats / 4
#define BLOCK 256
#define GRID  2048

__global__ __launch_bounds__(BLOCK) void slownorm_kernel(
    const float4* __restrict__ in, float4* __restrict__ out, unsigned int batch)
{
    const size_t n1 = (size_t)batch << 6;          // d=1 tasks
    const size_t n3 = (size_t)batch << 6;          // d=3 tasks
    const size_t n5 = (size_t)batch << 5;          // d=5 tasks
    const size_t n7 = (size_t)batch << 4;          // d=7 tasks
    const size_t b13  = n1 + n3;
    const size_t b135 = b13 + n5;
    const size_t ntot = b135 + n7;

    const size_t stride = (size_t)gridDim.x * BLOCK;
    for (size_t i = (size_t)blockIdx.x * BLOCK + threadIdx.x; i < ntot; i += stride) {
        size_t row;
        int    slot;
        float4 r;

        if (i < n1) {
            // d=1: norm of one element = |x|; 4 outputs from 1 float4
            row = i >> 6;
            const int s = (int)(i & 63);
            const float4 a = in[row * ROW4 + s];
            r.x = fabsf(a.x); r.y = fabsf(a.y); r.z = fabsf(a.z); r.w = fabsf(a.w);
            slot = s;
        } else if (i < b13) {
            // d=3: 12 floats = 3 float4 -> 4 norms
            const size_t j = i - n1;
            row = j >> 6;
            const int s = (int)(j & 63);
            const float4* __restrict__ p = in + row * ROW4 + 64 + (size_t)s * 3;
            const float4 a = p[0], b = p[1], c = p[2];
            r.x = sqrtf(a.x*a.x + a.y*a.y + a.z*a.z);
            r.y = sqrtf(a.w*a.w + b.x*b.x + b.y*b.y);
            r.z = sqrtf(b.z*b.z + b.w*b.w + c.x*c.x);
            r.w = sqrtf(c.y*c.y + c.z*c.z + c.w*c.w);
            slot = 64 + s;
        } else if (i < b135) {
            // d=5: 20 floats = 5 float4 -> 4 norms
            const size_t j = i - b13;
            row = j >> 5;
            const int s = (int)(j & 31);
            const float4* __restrict__ p = in + row * ROW4 + 256 + (size_t)s * 5;
            const float4 a = p[0], b = p[1], c = p[2], d = p[3], e = p[4];
            r.x = sqrtf(a.x*a.x + a.y*a.y + a.z*a.z + a.w*a.w + b.x*b.x);
            r.y = sqrtf(b.y*b.y + b.z*b.z + b.w*b.w + c.x*c.x + c.y*c.y);
            r.z = sqrtf(c.z*c.z + c.w*c.w + d.x*d.x + d.y*d.y + d.z*d.z);
            r.w = sqrtf(d.w*d.w + e.x*e.x + e.y*e.y + e.z*e.z + e.w*e.w);
            slot = 128 + s;
        } else {
            // d=7: 28 floats = 7 float4 -> 4 norms
            const size_t j = i - b135;
            row = j >> 4;
            const int s = (int)(j & 15);
            const float4* __restrict__ p = in + row * ROW4 + 416 + (size_t)s * 7;
            const float4 a = p[0], b = p[1], c = p[2], d = p[3], e = p[4], f = p[5], g = p[6];
            r.x = sqrtf(a.x*a.x + a.y*a.y + a.z*a.z + a.w*a.w + b.x*b.x + b.y*b.y + b.z*b.z);
            r.y = sqrtf(b.w*b.w + c.x*c.x + c.y*c.y + c.z*c.z + c.w*c.w + d.x*d.x + d.y*d.y);
            r.z = sqrtf(d.z*d.z + d.w*d.w + e.x*e.x + e.y*e.y + e.z*e.z + e.w*e.w + f.x*f.x);
            r.w = sqrtf(f.y*f.y + f.z*f.z + f.w*f.w + g.x*g.x + g.y*g.y + g.z*g.z + g.w*g.w);
            slot = 160 + s;
        }

        out[row * OUT4 + slot] = r;
    }
}

extern "C" void kernel_launch(void* const* d_in, const int* in_sizes, int n_in,
                              void* d_out, int out_size, void* d_ws, size_t ws_size,
                              hipStream_t stream)
{
    const float4* in  = (const float4*)d_in[0];
    float4*       out = (float4*)d_out;
    const unsigned int batch = (unsigned int)(in_sizes[0] / 2112);  // 65536

    const size_t ntot = (size_t)batch * 176;  // tasks total (11,534,336 @ 65536)
    unsigned int grid = (unsigned int)((ntot + BLOCK - 1) / BLOCK);
    if (grid > GRID) grid = GRID;

    slownorm_kernel<<<grid, BLOCK, 0, stream>>>(in, out, batch);
}